// Round 2
// baseline (282.786 us; speedup 1.0000x reference)
//
#include <hip/hip_runtime.h>
#include <hip/hip_bf16.h>
#include <math.h>

typedef __attribute__((ext_vector_type(8))) __bf16 bf16x8;
typedef __attribute__((ext_vector_type(4))) __bf16 bf16x4;
typedef __attribute__((ext_vector_type(4))) float f32x4;

#define B_ 4
#define T_ 2048
#define C_ 1024
#define H_ 16
#define D_ 64
#define M_TOT (B_*T_)

static __device__ __forceinline__ f32x4 mfma_bf16(bf16x8 a, bf16x8 b, f32x4 c) {
  return __builtin_amdgcn_mfma_f32_16x16x32_bf16(a, b, c, 0, 0, 0);
}

static __device__ __forceinline__ void gload_lds16(const void* g, void* l) {
  __builtin_amdgcn_global_load_lds((const __attribute__((address_space(1))) void*)g,
                                   (__attribute__((address_space(3))) void*)l, 16, 0, 0);
}

// ---------------- converts ----------------

__global__ void f32_to_bf16_k(const float* __restrict__ in, __bf16* __restrict__ out, int n4) {
  int i = blockIdx.x * blockDim.x + threadIdx.x;
  if (i < n4) {
    float4 v = ((const float4*)in)[i];
    bf16x4 o = { (__bf16)v.x, (__bf16)v.y, (__bf16)v.z, (__bf16)v.w };
    *(bf16x4*)(out + (size_t)i*4) = o;
  }
}

// out[n][k] = in[k][n], out bf16 (N x K), in fp32 (K x N)
__global__ void transpose_to_bf16(const float* __restrict__ in, __bf16* __restrict__ out, int K, int N) {
  __shared__ float tile[32][33];
  int n0 = blockIdx.x * 32, k0 = blockIdx.y * 32;
  int tx = threadIdx.x & 31, ty = threadIdx.x >> 5;
  #pragma unroll
  for (int r = ty; r < 32; r += 8) tile[r][tx] = in[(size_t)(k0 + r)*N + n0 + tx];
  __syncthreads();
  #pragma unroll
  for (int r = ty; r < 32; r += 8) out[(size_t)(n0 + r)*K + k0 + tx] = (__bf16)tile[tx][r];
}

__global__ void rope_tables_k(float* __restrict__ cosT, float* __restrict__ sinT) {
  int idx = blockIdx.x * 256 + threadIdx.x;   // T_*32 total
  int t = idx >> 5, d = idx & 31;
  float inv = powf(10000.0f, -((float)(2*d)) / 64.0f);
  float ang = (float)t * inv;
  cosT[idx] = cosf(ang);
  sinT[idx] = sinf(ang);
}

// V [bh][t][d] -> Vt [bh][d][t]
__global__ void __launch_bounds__(256)
vtrans_k(const __bf16* __restrict__ v, __bf16* __restrict__ vt) {
  __shared__ __bf16 tile[64][72];
  const int tid = threadIdx.x;
  const int bh = blockIdx.y;
  const int t0 = blockIdx.x * 64;
  const __bf16* src = v + ((size_t)bh*T_ + t0)*D_;
  #pragma unroll
  for (int c = 0; c < 2; ++c) {
    int idx = tid + c*256;
    int row = idx >> 3, col8 = (idx & 7) * 8;
    *(bf16x8*)&tile[row][col8] = *(const bf16x8*)(src + row*D_ + col8);
  }
  __syncthreads();
  __bf16* dst = vt + (size_t)bh*D_*T_ + t0;
  #pragma unroll
  for (int c = 0; c < 2; ++c) {
    int idx = tid + c*256;
    int d = idx >> 3, t8 = (idx & 7) * 8;
    bf16x8 ov;
    #pragma unroll
    for (int j = 0; j < 8; ++j) ov[j] = tile[t8 + j][d];
    *(bf16x8*)(dst + (size_t)d*T_ + t8) = ov;
  }
}

// ---------------- QKV GEMM: 256x256 tile, BK=64, 8 waves, dbuf, 1-barrier/K-tile ----
#define GBK 64

__global__ void __launch_bounds__(512, 2)
gemm256_qkv(const __bf16* __restrict__ A, const __bf16* __restrict__ Bt,
            __bf16* __restrict__ qout, __bf16* __restrict__ kout, __bf16* __restrict__ vout,
            const float* __restrict__ cosT, const float* __restrict__ sinT)
{
  __shared__ __attribute__((aligned(16))) __bf16 lA[2][256*GBK];  // 32 KB each
  __shared__ __attribute__((aligned(16))) __bf16 lB[2][256*GBK];
  const int tid = threadIdx.x;
  const int lane = tid & 63, wave = tid >> 6;
  const int wr = wave >> 2, wc = wave & 3;       // 2 x 4 wave grid
  const int l15 = lane & 15, lhi = lane >> 4;

  const int id = blockIdx.x;                     // 384 blocks (384 % 8 == 0)
  const int n8 = gridDim.x >> 3;
  const int swz = (id & 7) * n8 + (id >> 3);
  const int row0 = (swz & 31) * 256;             // M/256 = 32
  const int col0 = (swz >> 5) * 256;             // N/256 = 12

  f32x4 acc[8][4] = {};

  const size_t lda = 1024 * 2;                   // K bytes per row
  const char* Abase = (const char*)A + (size_t)row0 * lda;
  const char* Bbase = (const char*)Bt + (size_t)col0 * lda;

  auto STAGE = [&](int kt, int s) {
    #pragma unroll
    for (int c = 0; c < 4; ++c) {
      const int L = tid*16 + c*8192;
      const int row = L >> 7, colb = L & 127;
      const int sb = colb ^ ((row & 7) << 4);    // inverse swizzle on global source
      gload_lds16(Abase + (size_t)row*lda + kt*128 + sb, (char*)lA[s] + L);
      gload_lds16(Bbase + (size_t)row*lda + kt*128 + sb, (char*)lB[s] + L);
    }
  };

  STAGE(0, 0);
  asm volatile("s_waitcnt vmcnt(0)" ::: "memory");
  __syncthreads();

  for (int kt = 0; kt < 16; ++kt) {
    const int cur = kt & 1;
    if (kt < 15) STAGE(kt + 1, cur ^ 1);

    // B fragments: read once per K-tile (4 n-frags x 2 k-steps)
    bf16x8 bfr[4][2];
    #pragma unroll
    for (int n = 0; n < 4; ++n) {
      const int row = wc*64 + n*16 + l15;
      const int sw = (row & 7) << 4;
      #pragma unroll
      for (int ks = 0; ks < 2; ++ks)
        bfr[n][ks] = *(const bf16x8*)((const char*)lB[cur] + row*128 + ((ks*64 + lhi*16) ^ sw));
    }
    // 4 phases: 2 m-rows each, 16 MFMA per phase
    #pragma unroll
    for (int mp = 0; mp < 4; ++mp) {
      bf16x8 af[2][2];
      #pragma unroll
      for (int mm = 0; mm < 2; ++mm) {
        const int row = wr*128 + (mp*2 + mm)*16 + l15;
        const int sw = (row & 7) << 4;
        #pragma unroll
        for (int ks = 0; ks < 2; ++ks)
          af[mm][ks] = *(const bf16x8*)((const char*)lA[cur] + row*128 + ((ks*64 + lhi*16) ^ sw));
      }
      __builtin_amdgcn_s_setprio(1);
      #pragma unroll
      for (int mm = 0; mm < 2; ++mm)
        #pragma unroll
        for (int n = 0; n < 4; ++n)
          #pragma unroll
          for (int ks = 0; ks < 2; ++ks)
            acc[mp*2 + mm][n] = mfma_bf16(af[mm][ks], bfr[n][ks], acc[mp*2 + mm][n]);
      __builtin_amdgcn_s_setprio(0);
    }

    asm volatile("s_waitcnt vmcnt(0)" ::: "memory");
    __syncthreads();
  }

  // epilogue: RoPE on q,k; scatter to (B,H,T,D); q pre-scaled by 0.125*log2e
  const int slot = (col0 >> 6) + wc;
  const int which = slot >> 4;
  const int h = slot & 15;
  const float fsc = (which == 0) ? 0.18033688011112042f : 1.0f;
  #pragma unroll
  for (int m = 0; m < 8; ++m) {
    #pragma unroll
    for (int r = 0; r < 4; ++r) {
      const int grow = row0 + wr*128 + m*16 + lhi*4 + r;
      const int b = grow >> 11, t = grow & 2047;
      const size_t obase = ((size_t)(b*H_ + h)*T_ + t)*D_;
      if (which == 2) {
        #pragma unroll
        for (int n = 0; n < 4; ++n)
          vout[obase + n*16 + l15] = (__bf16)acc[m][n][r];
      } else {
        __bf16* dst = (which == 0) ? qout : kout;
        #pragma unroll
        for (int n = 0; n < 2; ++n) {
          const int d1 = n*16 + l15;            // [0,32)
          const float c = cosT[t*32 + d1];
          const float s = sinT[t*32 + d1];
          const float x1 = acc[m][n][r];
          const float x2 = acc[m][n+2][r];
          dst[obase + d1]      = (__bf16)((x1*c - x2*s) * fsc);
          dst[obase + d1 + 32] = (__bf16)((x1*s + x2*c) * fsc);
        }
      }
    }
  }
}

// ---------------- out-proj GEMM (m97 structure: 128x128 tile, BK=64, 4 waves) -------
#define BM 128
#define BN 128
#define BK 64

__global__ void __launch_bounds__(256)
gemm_out(const __bf16* __restrict__ A, const __bf16* __restrict__ Bt, int K,
         float* __restrict__ fout, const float* __restrict__ bias)
{
  __shared__ __bf16 lA[BM*BK];
  __shared__ __bf16 lB[BN*BK];
  const int tid = threadIdx.x;
  const int lane = tid & 63, wave = tid >> 6;
  const int wr = wave >> 1, wc = wave & 1;
  const int l15 = lane & 15, lhi = lane >> 4;

  const int id = blockIdx.x;
  const int n8 = gridDim.x >> 3;
  const int swz = (id & 7) * n8 + (id >> 3);
  const int row0 = (swz & 63) * BM;
  const int col0 = (swz >> 6) * BN;

  f32x4 acc[4][4] = {};

  const int stago = wave*1024 + lane*16;
  const size_t arow0 = (size_t)row0 * (size_t)(K*2);
  const size_t brow0 = (size_t)col0 * (size_t)(K*2);

  for (int k0 = 0; k0 < K; k0 += BK) {
    #pragma unroll
    for (int r = 0; r < 4; ++r) {
      int ob = stago + r*4096;
      int row = ob >> 7;
      int colb = ob & 127;
      gload_lds16((const char*)A + arow0 + (size_t)row*(size_t)(K*2) + (size_t)(k0*2 + colb),
                  (char*)lA + ob);
      gload_lds16((const char*)Bt + brow0 + (size_t)row*(size_t)(K*2) + (size_t)(k0*2 + colb),
                  (char*)lB + ob);
    }
    __syncthreads();
    #pragma unroll
    for (int kk = 0; kk < BK; kk += 32) {
      bf16x8 af[4], bfr[4];
      #pragma unroll
      for (int m = 0; m < 4; ++m)
        af[m] = *(const bf16x8*)&lA[(wr*64 + m*16 + l15)*BK + kk + lhi*8];
      #pragma unroll
      for (int n = 0; n < 4; ++n)
        bfr[n] = *(const bf16x8*)&lB[(wc*64 + n*16 + l15)*BK + kk + lhi*8];
      #pragma unroll
      for (int m = 0; m < 4; ++m)
        #pragma unroll
        for (int n = 0; n < 4; ++n)
          acc[m][n] = mfma_bf16(af[m], bfr[n], acc[m][n]);
    }
    __syncthreads();
  }

  #pragma unroll
  for (int m = 0; m < 4; ++m) {
    #pragma unroll
    for (int r = 0; r < 4; ++r) {
      const int grow = row0 + wr*64 + m*16 + lhi*4 + r;
      #pragma unroll
      for (int n = 0; n < 4; ++n) {
        const int gcol = col0 + wc*64 + n*16 + l15;
        fout[(size_t)grow*1024 + gcol] = acc[m][n][r] + bias[gcol];
      }
    }
  }
}

// ---------------- flash attention: split-KV + LPT ----------------
// 1536 blocks. qblock>=8 split into 2 kv-chunks (<=16 iters each) writing f32
// partials (O, m, l) merged by attn_combine; qblock<8 direct. Static LPT order.
// Single-buffered K/V (dbuf proven neutral) -> LDS 32KB -> 4 blocks/CU.
#define THR_LOG2 8.0f

// group (blockIdx>>6) -> qblock, split (0/1 = kv half, 2 = direct full range)
static __device__ const char QB_TAB[24] = {15,15,7,14,14,13,13,6,12,12,11,11,5,10,10,9,9,4,8,8,3,2,1,0};
static __device__ const char SP_TAB[24] = { 0, 1,2, 0, 1, 0, 1,2, 0, 1, 0, 1,2, 0, 1,0,1,2,0,1,2,2,2,2};

__global__ void __launch_bounds__(256, 4)
attn_kernel(const __bf16* __restrict__ q, const __bf16* __restrict__ k,
            const __bf16* __restrict__ vt, const int* __restrict__ amask,
            __bf16* __restrict__ aout,
            float* __restrict__ pO, float* __restrict__ pM, float* __restrict__ pL)
{
  __shared__ __attribute__((aligned(16))) __bf16 lK[64*64];    // 8 KB
  __shared__ __attribute__((aligned(16))) __bf16 lVt[64*64];   // 8 KB
  __shared__ __attribute__((aligned(16))) __bf16 lP[4][32*64]; // 16 KB
  const int tid = threadIdx.x;
  const int lane = tid & 63, wave = tid >> 6;
  const int l15 = lane & 15, lhi = lane >> 4;

  const int g = blockIdx.x >> 6;
  const int bh = blockIdx.x & 63;
  const int qblock = QB_TAB[g];
  const int sp = SP_TAB[g];
  const int kb0   = (sp == 1) ? (qblock + 1) : 0;
  const int kbend = (sp == 0) ? (qblock + 1) : (2*qblock + 2);

  const int b = bh >> 4, h = bh & 15;
  const size_t kvbase = (size_t)bh * T_ * D_;
  const char* kbase  = (const char*)(k + kvbase);
  const char* vtbase = (const char*)(vt + kvbase);
  char* lPw = (char*)lP[wave];

  const int q0w = qblock*128 + wave*32;

  bf16x8 aq[2][2];
  #pragma unroll
  for (int m = 0; m < 2; ++m)
    #pragma unroll
    for (int ks = 0; ks < 2; ++ks)
      aq[m][ks] = *(const bf16x8*)(q + kvbase + (size_t)(q0w + m*16 + l15)*D_ + ks*32 + lhi*8);

  f32x4 acc_o[2][4] = {};
  f32x4 acc_l[2] = {};
  float m_w = -3e37f;

  for (int kb = kb0; kb < kbend; ++kb) {
    #pragma unroll
    for (int c = 0; c < 2; ++c) {
      const int L = tid*16 + c*4096;
      const int row = L >> 7;
      const int sb  = (L & 127) ^ ((row & 7) << 4);
      gload_lds16(kbase  + (size_t)(kb*64 + row)*128 + sb, (char*)lK + L);
      gload_lds16(vtbase + (size_t)row*(T_*2) + (size_t)kb*128 + sb, (char*)lVt + L);
    }
    __syncthreads();

    if (kb*64 <= q0w + 31) {
      const char* lKc = (const char*)lK;
      const char* lVc = (const char*)lVt;

      f32x4 sc[2][4] = {};
      __builtin_amdgcn_s_setprio(1);
      #pragma unroll
      for (int n = 0; n < 4; ++n) {
        const int row = n*16 + l15;
        const int sw = (row & 7) << 4;
        #pragma unroll
        for (int ks = 0; ks < 2; ++ks) {
          bf16x8 bk = *(const bf16x8*)(lKc + row*128 + ((ks*64 + lhi*16) ^ sw));
          #pragma unroll
          for (int m = 0; m < 2; ++m)
            sc[m][n] = mfma_bf16(aq[m][ks], bk, sc[m][n]);
        }
      }
      __builtin_amdgcn_s_setprio(0);

      if (kb*64 + 63 > q0w) {
        #pragma unroll
        for (int m = 0; m < 2; ++m)
          #pragma unroll
          for (int r = 0; r < 4; ++r) {
            const int tq = q0w + m*16 + lhi*4 + r;
            #pragma unroll
            for (int n = 0; n < 4; ++n)
              if (kb*64 + n*16 + l15 > tq) sc[m][n][r] = -3e37f;
          }
      }

      f32x4 vm = sc[0][0];
      #pragma unroll
      for (int m = 0; m < 2; ++m)
        #pragma unroll
        for (int n = 0; n < 4; ++n) {
          if (m == 0 && n == 0) continue;
          #pragma unroll
          for (int r = 0; r < 4; ++r) vm[r] = fmaxf(vm[r], sc[m][n][r]);
        }
      float tmax = fmaxf(fmaxf(vm[0], vm[1]), fmaxf(vm[2], vm[3]));
      #pragma unroll
      for (int off = 1; off < 64; off <<= 1)
        tmax = fmaxf(tmax, __shfl_xor(tmax, off));

      if (tmax > m_w + THR_LOG2) {
        const float corr = __builtin_amdgcn_exp2f(m_w - tmax);
        #pragma unroll
        for (int m = 0; m < 2; ++m) {
          #pragma unroll
          for (int c = 0; c < 4; ++c) acc_o[m][c] *= corr;
          acc_l[m] *= corr;
        }
        m_w = tmax;
      }

      float mk[4];
      #pragma unroll
      for (int n = 0; n < 4; ++n)
        mk[n] = (amask[b*T_ + kb*64 + n*16 + l15] != 0) ? m_w : 3e37f;

      #pragma unroll
      for (int m = 0; m < 2; ++m)
        #pragma unroll
        for (int r = 0; r < 4; ++r) {
          const int row = m*16 + lhi*4 + r;
          const int sw = (row & 7) << 4;
          #pragma unroll
          for (int n = 0; n < 4; ++n) {
            const float p = __builtin_amdgcn_exp2f(sc[m][n][r] - mk[n]);
            *(__bf16*)(lPw + row*128 + ((((n*16 + l15)*2)) ^ sw)) = (__bf16)p;
          }
        }

      bf16x8 pa[2][2];
      #pragma unroll
      for (int m = 0; m < 2; ++m) {
        const int row = m*16 + l15;
        const int sw = (row & 7) << 4;
        #pragma unroll
        for (int ks = 0; ks < 2; ++ks)
          pa[m][ks] = *(const bf16x8*)(lPw + row*128 + ((ks*64 + lhi*16) ^ sw));
      }

      __builtin_amdgcn_s_setprio(1);
      const __bf16 one = (__bf16)1.0f;
      const bf16x8 vone = {one, one, one, one, one, one, one, one};
      #pragma unroll
      for (int m = 0; m < 2; ++m)
        #pragma unroll
        for (int ks = 0; ks < 2; ++ks)
          acc_l[m] = mfma_bf16(pa[m][ks], vone, acc_l[m]);

      #pragma unroll
      for (int c = 0; c < 4; ++c) {
        const int row = c*16 + l15;
        const int sw = (row & 7) << 4;
        #pragma unroll
        for (int ks = 0; ks < 2; ++ks) {
          bf16x8 bv = *(const bf16x8*)(lVc + row*128 + ((ks*64 + lhi*16) ^ sw));
          #pragma unroll
          for (int m = 0; m < 2; ++m)
            acc_o[m][c] = mfma_bf16(pa[m][ks], bv, acc_o[m][c]);
        }
      }
      __builtin_amdgcn_s_setprio(0);
    }
    __syncthreads();
  }

  if (sp == 2) {
    // direct: normalize and write
    #pragma unroll
    for (int m = 0; m < 2; ++m)
      #pragma unroll
      for (int r = 0; r < 4; ++r) {
        const int tq = q0w + m*16 + lhi*4 + r;
        const float invl = 1.0f / acc_l[m][r];
        const size_t obase = ((size_t)b*T_ + tq)*C_ + h*D_;
        #pragma unroll
        for (int c = 0; c < 4; ++c)
          aout[obase + c*16 + l15] = (__bf16)(acc_o[m][c][r] * invl);
      }
  } else {
    // partial: unnormalized O (f32) + per-row m, l
    const int pidx = ((qblock - 8)*2 + sp)*64 + bh;
    float* po = pO + (size_t)pidx*128*64;
    float* pm = pM + pidx*128;
    float* pl = pL + pidx*128;
    #pragma unroll
    for (int m = 0; m < 2; ++m)
      #pragma unroll
      for (int r = 0; r < 4; ++r) {
        const int rw = wave*32 + m*16 + lhi*4 + r;
        if (l15 == 0) { pm[rw] = m_w; pl[rw] = acc_l[m][r]; }
        #pragma unroll
        for (int c = 0; c < 4; ++c)
          po[(size_t)rw*64 + c*16 + l15] = acc_o[m][c][r];
      }
  }
}

// merge the two kv-split partials for qblock in [8,16)
__global__ void __launch_bounds__(256)
attn_combine(const float* __restrict__ pO, const float* __restrict__ pM,
             const float* __restrict__ pL, __bf16* __restrict__ aout)
{
  const int g = blockIdx.x;            // 512: qb8*64 + bh
  const int qb8 = g >> 6, bh = g & 63;
  const int p0 = (qb8*2)*64 + bh, p1 = (qb8*2 + 1)*64 + bh;
  const int row = threadIdx.x >> 1, ch = threadIdx.x & 1;
  const float m0 = pM[p0*128 + row], m1 = pM[p1*128 + row];
  const float l0 = pL[p0*128 + row], l1 = pL[p1*128 + row];
  const float M = fmaxf(m0, m1);
  const float w0 = __builtin_amdgcn_exp2f(m0 - M);
  const float w1 = __builtin_amdgcn_exp2f(m1 - M);
  const float inv = 1.0f / (l0*w0 + l1*w1);
  const int b = bh >> 4, h = bh & 15;
  const int t = (qb8 + 8)*128 + row;
  const float* o0 = pO + ((size_t)p0*128 + row)*64 + ch*32;
  const float* o1 = pO + ((size_t)p1*128 + row)*64 + ch*32;
  __bf16* dst = aout + ((size_t)b*T_ + t)*C_ + h*D_ + ch*32;
  #pragma unroll
  for (int j = 0; j < 32; j += 4) {
    float4 a = *(const float4*)(o0 + j);
    float4 c = *(const float4*)(o1 + j);
    bf16x4 rr;
    rr[0] = (__bf16)((a.x*w0 + c.x*w1) * inv);
    rr[1] = (__bf16)((a.y*w0 + c.y*w1) * inv);
    rr[2] = (__bf16)((a.z*w0 + c.z*w1) * inv);
    rr[3] = (__bf16)((a.w*w0 + c.w*w1) * inv);
    *(bf16x4*)(dst + j) = rr;
  }
}

// ---------------- launch ----------------

extern "C" void kernel_launch(void* const* d_in, const int* in_sizes, int n_in,
                              void* d_out, int out_size, void* d_ws, size_t ws_size,
                              hipStream_t stream)
{
  const float* x     = (const float*)d_in[0];
  const int*   amask = (const int*)d_in[1];
  const float* Wqkv  = (const float*)d_in[2];
  const float* Wout  = (const float*)d_in[3];
  const float* bout  = (const float*)d_in[4];
  float* out = (float*)d_out;

  char* w = (char*)d_ws;
  __bf16* xb    = (__bf16*)w;  w += (size_t)M_TOT*C_*2;       // 16 MB (reused as vtb after QKV GEMM)
  __bf16* wqkvT = (__bf16*)w;  w += (size_t)3072*1024*2;      // 6 MB
  __bf16* woutT = (__bf16*)w;  w += (size_t)1024*1024*2;      // 2 MB
  __bf16* qb    = (__bf16*)w;  w += (size_t)B_*H_*T_*D_*2;    // 16 MB
  __bf16* kb    = (__bf16*)w;  w += (size_t)B_*H_*T_*D_*2;    // 16 MB
  __bf16* vb    = (__bf16*)w;  w += (size_t)B_*H_*T_*D_*2;    // 16 MB
  __bf16* aob   = (__bf16*)w;  w += (size_t)M_TOT*C_*2;       // 16 MB
  float*  cosT  = (float*)w;   w += (size_t)T_*32*4;
  float*  sinT  = (float*)w;   w += (size_t)T_*32*4;
  float*  pO    = (float*)w;   w += (size_t)1024*128*64*4;    // 33.5 MB split partials
  float*  pM    = (float*)w;   w += (size_t)1024*128*4;
  float*  pL    = (float*)w;   w += (size_t)1024*128*4;
  __bf16* vtb   = xb;   // xb dead after QKV GEMM; alias for V^T

  f32_to_bf16_k<<<(M_TOT*C_/4 + 255)/256, 256, 0, stream>>>(x, xb, M_TOT*C_/4);
  transpose_to_bf16<<<dim3(96, 32), 256, 0, stream>>>(Wqkv, wqkvT, 1024, 3072);
  transpose_to_bf16<<<dim3(32, 32), 256, 0, stream>>>(Wout, woutT, 1024, 1024);
  rope_tables_k<<<(T_*32)/256, 256, 0, stream>>>(cosT, sinT);

  gemm256_qkv<<<dim3(384), 512, 0, stream>>>(xb, wqkvT, qb, kb, vb, cosT, sinT);

  vtrans_k<<<dim3(T_/64, B_*H_), 256, 0, stream>>>(vb, vtb);

  attn_kernel<<<dim3(1536), 256, 0, stream>>>(qb, kb, vtb, amask, aob, pO, pM, pL);
  attn_combine<<<dim3(512), 256, 0, stream>>>(pO, pM, pL, aob);

  gemm_out<<<dim3(64*8), 256, 0, stream>>>(
      aob, woutT, 1024, out, bout);
}

// Round 3
// 244.381 us; speedup vs baseline: 1.1572x; 1.1572x over previous
//
#include <hip/hip_runtime.h>
#include <hip/hip_bf16.h>
#include <math.h>

typedef __attribute__((ext_vector_type(8))) __bf16 bf16x8;
typedef __attribute__((ext_vector_type(4))) __bf16 bf16x4;
typedef __attribute__((ext_vector_type(4))) float f32x4;

#define B_ 4
#define T_ 2048
#define C_ 1024
#define H_ 16
#define D_ 64
#define M_TOT (B_*T_)

static __device__ __forceinline__ f32x4 mfma_bf16(bf16x8 a, bf16x8 b, f32x4 c) {
  return __builtin_amdgcn_mfma_f32_16x16x32_bf16(a, b, c, 0, 0, 0);
}

static __device__ __forceinline__ void gload_lds16(const void* g, void* l) {
  __builtin_amdgcn_global_load_lds((const __attribute__((address_space(1))) void*)g,
                                   (__attribute__((address_space(3))) void*)l, 16, 0, 0);
}

// ---------------- converts ----------------

__global__ void f32_to_bf16_k(const float* __restrict__ in, __bf16* __restrict__ out, int n4) {
  int i = blockIdx.x * blockDim.x + threadIdx.x;
  if (i < n4) {
    float4 v = ((const float4*)in)[i];
    bf16x4 o = { (__bf16)v.x, (__bf16)v.y, (__bf16)v.z, (__bf16)v.w };
    *(bf16x4*)(out + (size_t)i*4) = o;
  }
}

// out[n][k] = in[k][n], out bf16 (N x K), in fp32 (K x N)
__global__ void transpose_to_bf16(const float* __restrict__ in, __bf16* __restrict__ out, int K, int N) {
  __shared__ float tile[32][33];
  int n0 = blockIdx.x * 32, k0 = blockIdx.y * 32;
  int tx = threadIdx.x & 31, ty = threadIdx.x >> 5;
  #pragma unroll
  for (int r = ty; r < 32; r += 8) tile[r][tx] = in[(size_t)(k0 + r)*N + n0 + tx];
  __syncthreads();
  #pragma unroll
  for (int r = ty; r < 32; r += 8) out[(size_t)(n0 + r)*K + k0 + tx] = (__bf16)tile[tx][r];
}

__global__ void rope_tables_k(float* __restrict__ cosT, float* __restrict__ sinT) {
  int idx = blockIdx.x * 256 + threadIdx.x;   // T_*32 total
  int t = idx >> 5, d = idx & 31;
  float inv = powf(10000.0f, -((float)(2*d)) / 64.0f);
  float ang = (float)t * inv;
  cosT[idx] = cosf(ang);
  sinT[idx] = sinf(ang);
}

// V [bh][t][d] -> Vt [bh][d][t]
__global__ void __launch_bounds__(256)
vtrans_k(const __bf16* __restrict__ v, __bf16* __restrict__ vt) {
  __shared__ __bf16 tile[64][72];
  const int tid = threadIdx.x;
  const int bh = blockIdx.y;
  const int t0 = blockIdx.x * 64;
  const __bf16* src = v + ((size_t)bh*T_ + t0)*D_;
  #pragma unroll
  for (int c = 0; c < 2; ++c) {
    int idx = tid + c*256;
    int row = idx >> 3, col8 = (idx & 7) * 8;
    *(bf16x8*)&tile[row][col8] = *(const bf16x8*)(src + row*D_ + col8);
  }
  __syncthreads();
  __bf16* dst = vt + (size_t)bh*D_*T_ + t0;
  #pragma unroll
  for (int c = 0; c < 2; ++c) {
    int idx = tid + c*256;
    int d = idx >> 3, t8 = (idx & 7) * 8;
    bf16x8 ov;
    #pragma unroll
    for (int j = 0; j < 8; ++j) ov[j] = tile[t8 + j][d];
    *(bf16x8*)(dst + (size_t)d*T_ + t8) = ov;
  }
}

// ---------------- QKV GEMM: 256x256 tile, BK=64, 8 waves, dbuf, 1-barrier/K-tile ----
#define GBK 64

__global__ void __launch_bounds__(512, 2)
gemm256_qkv(const __bf16* __restrict__ A, const __bf16* __restrict__ Bt,
            __bf16* __restrict__ qout, __bf16* __restrict__ kout, __bf16* __restrict__ vout,
            const float* __restrict__ cosT, const float* __restrict__ sinT)
{
  __shared__ __attribute__((aligned(16))) __bf16 lA[2][256*GBK];  // 32 KB each
  __shared__ __attribute__((aligned(16))) __bf16 lB[2][256*GBK];
  const int tid = threadIdx.x;
  const int lane = tid & 63, wave = tid >> 6;
  const int wr = wave >> 2, wc = wave & 3;       // 2 x 4 wave grid
  const int l15 = lane & 15, lhi = lane >> 4;

  const int id = blockIdx.x;                     // 384 blocks (384 % 8 == 0)
  const int n8 = gridDim.x >> 3;
  const int swz = (id & 7) * n8 + (id >> 3);
  const int row0 = (swz & 31) * 256;             // M/256 = 32
  const int col0 = (swz >> 5) * 256;             // N/256 = 12

  f32x4 acc[8][4] = {};

  const size_t lda = 1024 * 2;                   // K bytes per row
  const char* Abase = (const char*)A + (size_t)row0 * lda;
  const char* Bbase = (const char*)Bt + (size_t)col0 * lda;

  auto STAGE = [&](int kt, int s) {
    #pragma unroll
    for (int c = 0; c < 4; ++c) {
      const int L = tid*16 + c*8192;
      const int row = L >> 7, colb = L & 127;
      const int sb = colb ^ ((row & 7) << 4);    // inverse swizzle on global source
      gload_lds16(Abase + (size_t)row*lda + kt*128 + sb, (char*)lA[s] + L);
      gload_lds16(Bbase + (size_t)row*lda + kt*128 + sb, (char*)lB[s] + L);
    }
  };

  STAGE(0, 0);
  asm volatile("s_waitcnt vmcnt(0)" ::: "memory");
  __syncthreads();

  for (int kt = 0; kt < 16; ++kt) {
    const int cur = kt & 1;
    if (kt < 15) STAGE(kt + 1, cur ^ 1);

    // B fragments: read once per K-tile (4 n-frags x 2 k-steps)
    bf16x8 bfr[4][2];
    #pragma unroll
    for (int n = 0; n < 4; ++n) {
      const int row = wc*64 + n*16 + l15;
      const int sw = (row & 7) << 4;
      #pragma unroll
      for (int ks = 0; ks < 2; ++ks)
        bfr[n][ks] = *(const bf16x8*)((const char*)lB[cur] + row*128 + ((ks*64 + lhi*16) ^ sw));
    }
    // 4 phases: 2 m-rows each, 16 MFMA per phase
    #pragma unroll
    for (int mp = 0; mp < 4; ++mp) {
      bf16x8 af[2][2];
      #pragma unroll
      for (int mm = 0; mm < 2; ++mm) {
        const int row = wr*128 + (mp*2 + mm)*16 + l15;
        const int sw = (row & 7) << 4;
        #pragma unroll
        for (int ks = 0; ks < 2; ++ks)
          af[mm][ks] = *(const bf16x8*)((const char*)lA[cur] + row*128 + ((ks*64 + lhi*16) ^ sw));
      }
      __builtin_amdgcn_s_setprio(1);
      #pragma unroll
      for (int mm = 0; mm < 2; ++mm)
        #pragma unroll
        for (int n = 0; n < 4; ++n)
          #pragma unroll
          for (int ks = 0; ks < 2; ++ks)
            acc[mp*2 + mm][n] = mfma_bf16(af[mm][ks], bfr[n][ks], acc[mp*2 + mm][n]);
      __builtin_amdgcn_s_setprio(0);
    }

    asm volatile("s_waitcnt vmcnt(0)" ::: "memory");
    __syncthreads();
  }

  // epilogue: RoPE on q,k; scatter to (B,H,T,D); q pre-scaled by 0.125*log2e
  const int slot = (col0 >> 6) + wc;
  const int which = slot >> 4;
  const int h = slot & 15;
  const float fsc = (which == 0) ? 0.18033688011112042f : 1.0f;
  #pragma unroll
  for (int m = 0; m < 8; ++m) {
    #pragma unroll
    for (int r = 0; r < 4; ++r) {
      const int grow = row0 + wr*128 + m*16 + lhi*4 + r;
      const int b = grow >> 11, t = grow & 2047;
      const size_t obase = ((size_t)(b*H_ + h)*T_ + t)*D_;
      if (which == 2) {
        #pragma unroll
        for (int n = 0; n < 4; ++n)
          vout[obase + n*16 + l15] = (__bf16)acc[m][n][r];
      } else {
        __bf16* dst = (which == 0) ? qout : kout;
        #pragma unroll
        for (int n = 0; n < 2; ++n) {
          const int d1 = n*16 + l15;            // [0,32)
          const float c = cosT[t*32 + d1];
          const float s = sinT[t*32 + d1];
          const float x1 = acc[m][n][r];
          const float x2 = acc[m][n+2][r];
          dst[obase + d1]      = (__bf16)((x1*c - x2*s) * fsc);
          dst[obase + d1 + 32] = (__bf16)((x1*s + x2*c) * fsc);
        }
      }
    }
  }
}

// ---------------- out-proj GEMM (m97 structure: 128x128 tile, BK=64, 4 waves) -------
#define BM 128
#define BN 128
#define BK 64

__global__ void __launch_bounds__(256)
gemm_out(const __bf16* __restrict__ A, const __bf16* __restrict__ Bt, int K,
         float* __restrict__ fout, const float* __restrict__ bias)
{
  __shared__ __bf16 lA[BM*BK];
  __shared__ __bf16 lB[BN*BK];
  const int tid = threadIdx.x;
  const int lane = tid & 63, wave = tid >> 6;
  const int wr = wave >> 1, wc = wave & 1;
  const int l15 = lane & 15, lhi = lane >> 4;

  const int id = blockIdx.x;
  const int n8 = gridDim.x >> 3;
  const int swz = (id & 7) * n8 + (id >> 3);
  const int row0 = (swz & 63) * BM;
  const int col0 = (swz >> 6) * BN;

  f32x4 acc[4][4] = {};

  const int stago = wave*1024 + lane*16;
  const size_t arow0 = (size_t)row0 * (size_t)(K*2);
  const size_t brow0 = (size_t)col0 * (size_t)(K*2);

  for (int k0 = 0; k0 < K; k0 += BK) {
    #pragma unroll
    for (int r = 0; r < 4; ++r) {
      int ob = stago + r*4096;
      int row = ob >> 7;
      int colb = ob & 127;
      gload_lds16((const char*)A + arow0 + (size_t)row*(size_t)(K*2) + (size_t)(k0*2 + colb),
                  (char*)lA + ob);
      gload_lds16((const char*)Bt + brow0 + (size_t)row*(size_t)(K*2) + (size_t)(k0*2 + colb),
                  (char*)lB + ob);
    }
    __syncthreads();
    #pragma unroll
    for (int kk = 0; kk < BK; kk += 32) {
      bf16x8 af[4], bfr[4];
      #pragma unroll
      for (int m = 0; m < 4; ++m)
        af[m] = *(const bf16x8*)&lA[(wr*64 + m*16 + l15)*BK + kk + lhi*8];
      #pragma unroll
      for (int n = 0; n < 4; ++n)
        bfr[n] = *(const bf16x8*)&lB[(wc*64 + n*16 + l15)*BK + kk + lhi*8];
      #pragma unroll
      for (int m = 0; m < 4; ++m)
        #pragma unroll
        for (int n = 0; n < 4; ++n)
          acc[m][n] = mfma_bf16(af[m], bfr[n], acc[m][n]);
    }
    __syncthreads();
  }

  #pragma unroll
  for (int m = 0; m < 4; ++m) {
    #pragma unroll
    for (int r = 0; r < 4; ++r) {
      const int grow = row0 + wr*64 + m*16 + lhi*4 + r;
      #pragma unroll
      for (int n = 0; n < 4; ++n) {
        const int gcol = col0 + wc*64 + n*16 + l15;
        fout[(size_t)grow*1024 + gcol] = acc[m][n][r] + bias[gcol];
      }
    }
  }
}

// ---------------- flash attention: split-KV + LPT ----------------
// 1536 blocks. qblock>=8 split into 2 kv-chunks (<=16 iters each) writing f32
// partials (O, m, l) merged by attn_combine; qblock<8 direct. Static LPT order.
// Single-buffered K/V -> LDS 32KB. NOTE: plain __launch_bounds__(256) — the
// round-2 (256,4) variant forced VGPR to 64 and spilled accumulators to
// scratch (WRITE_SIZE 191MB). Default bounds restore ~116 VGPR, no spill.
#define THR_LOG2 8.0f

// group (blockIdx>>6) -> qblock, split (0/1 = kv half, 2 = direct full range)
static __device__ const char QB_TAB[24] = {15,15,7,14,14,13,13,6,12,12,11,11,5,10,10,9,9,4,8,8,3,2,1,0};
static __device__ const char SP_TAB[24] = { 0, 1,2, 0, 1, 0, 1,2, 0, 1, 0, 1,2, 0, 1,0,1,2,0,1,2,2,2,2};

__global__ void __launch_bounds__(256)
attn_kernel(const __bf16* __restrict__ q, const __bf16* __restrict__ k,
            const __bf16* __restrict__ vt, const int* __restrict__ amask,
            __bf16* __restrict__ aout,
            float* __restrict__ pO, float* __restrict__ pM, float* __restrict__ pL)
{
  __shared__ __attribute__((aligned(16))) __bf16 lK[64*64];    // 8 KB
  __shared__ __attribute__((aligned(16))) __bf16 lVt[64*64];   // 8 KB
  __shared__ __attribute__((aligned(16))) __bf16 lP[4][32*64]; // 16 KB
  const int tid = threadIdx.x;
  const int lane = tid & 63, wave = tid >> 6;
  const int l15 = lane & 15, lhi = lane >> 4;

  const int g = blockIdx.x >> 6;
  const int bh = blockIdx.x & 63;
  const int qblock = QB_TAB[g];
  const int sp = SP_TAB[g];
  const int kb0   = (sp == 1) ? (qblock + 1) : 0;
  const int kbend = (sp == 0) ? (qblock + 1) : (2*qblock + 2);

  const int b = bh >> 4, h = bh & 15;
  const size_t kvbase = (size_t)bh * T_ * D_;
  const char* kbase  = (const char*)(k + kvbase);
  const char* vtbase = (const char*)(vt + kvbase);
  char* lPw = (char*)lP[wave];

  const int q0w = qblock*128 + wave*32;

  bf16x8 aq[2][2];
  #pragma unroll
  for (int m = 0; m < 2; ++m)
    #pragma unroll
    for (int ks = 0; ks < 2; ++ks)
      aq[m][ks] = *(const bf16x8*)(q + kvbase + (size_t)(q0w + m*16 + l15)*D_ + ks*32 + lhi*8);

  f32x4 acc_o[2][4] = {};
  f32x4 acc_l[2] = {};
  float m_w = -3e37f;

  for (int kb = kb0; kb < kbend; ++kb) {
    #pragma unroll
    for (int c = 0; c < 2; ++c) {
      const int L = tid*16 + c*4096;
      const int row = L >> 7;
      const int sb  = (L & 127) ^ ((row & 7) << 4);
      gload_lds16(kbase  + (size_t)(kb*64 + row)*128 + sb, (char*)lK + L);
      gload_lds16(vtbase + (size_t)row*(T_*2) + (size_t)kb*128 + sb, (char*)lVt + L);
    }
    __syncthreads();

    if (kb*64 <= q0w + 31) {
      const char* lKc = (const char*)lK;
      const char* lVc = (const char*)lVt;

      f32x4 sc[2][4] = {};
      __builtin_amdgcn_s_setprio(1);
      #pragma unroll
      for (int n = 0; n < 4; ++n) {
        const int row = n*16 + l15;
        const int sw = (row & 7) << 4;
        #pragma unroll
        for (int ks = 0; ks < 2; ++ks) {
          bf16x8 bk = *(const bf16x8*)(lKc + row*128 + ((ks*64 + lhi*16) ^ sw));
          #pragma unroll
          for (int m = 0; m < 2; ++m)
            sc[m][n] = mfma_bf16(aq[m][ks], bk, sc[m][n]);
        }
      }
      __builtin_amdgcn_s_setprio(0);

      if (kb*64 + 63 > q0w) {
        #pragma unroll
        for (int m = 0; m < 2; ++m)
          #pragma unroll
          for (int r = 0; r < 4; ++r) {
            const int tq = q0w + m*16 + lhi*4 + r;
            #pragma unroll
            for (int n = 0; n < 4; ++n)
              if (kb*64 + n*16 + l15 > tq) sc[m][n][r] = -3e37f;
          }
      }

      f32x4 vm = sc[0][0];
      #pragma unroll
      for (int m = 0; m < 2; ++m)
        #pragma unroll
        for (int n = 0; n < 4; ++n) {
          if (m == 0 && n == 0) continue;
          #pragma unroll
          for (int r = 0; r < 4; ++r) vm[r] = fmaxf(vm[r], sc[m][n][r]);
        }
      float tmax = fmaxf(fmaxf(vm[0], vm[1]), fmaxf(vm[2], vm[3]));
      #pragma unroll
      for (int off = 1; off < 64; off <<= 1)
        tmax = fmaxf(tmax, __shfl_xor(tmax, off));

      if (tmax > m_w + THR_LOG2) {
        const float corr = __builtin_amdgcn_exp2f(m_w - tmax);
        #pragma unroll
        for (int m = 0; m < 2; ++m) {
          #pragma unroll
          for (int c = 0; c < 4; ++c) acc_o[m][c] *= corr;
          acc_l[m] *= corr;
        }
        m_w = tmax;
      }

      float mk[4];
      #pragma unroll
      for (int n = 0; n < 4; ++n)
        mk[n] = (amask[b*T_ + kb*64 + n*16 + l15] != 0) ? m_w : 3e37f;

      #pragma unroll
      for (int m = 0; m < 2; ++m)
        #pragma unroll
        for (int r = 0; r < 4; ++r) {
          const int row = m*16 + lhi*4 + r;
          const int sw = (row & 7) << 4;
          #pragma unroll
          for (int n = 0; n < 4; ++n) {
            const float p = __builtin_amdgcn_exp2f(sc[m][n][r] - mk[n]);
            *(__bf16*)(lPw + row*128 + ((((n*16 + l15)*2)) ^ sw)) = (__bf16)p;
          }
        }

      bf16x8 pa[2][2];
      #pragma unroll
      for (int m = 0; m < 2; ++m) {
        const int row = m*16 + l15;
        const int sw = (row & 7) << 4;
        #pragma unroll
        for (int ks = 0; ks < 2; ++ks)
          pa[m][ks] = *(const bf16x8*)(lPw + row*128 + ((ks*64 + lhi*16) ^ sw));
      }

      __builtin_amdgcn_s_setprio(1);
      const __bf16 one = (__bf16)1.0f;
      const bf16x8 vone = {one, one, one, one, one, one, one, one};
      #pragma unroll
      for (int m = 0; m < 2; ++m)
        #pragma unroll
        for (int ks = 0; ks < 2; ++ks)
          acc_l[m] = mfma_bf16(pa[m][ks], vone, acc_l[m]);

      #pragma unroll
      for (int c = 0; c < 4; ++c) {
        const int row = c*16 + l15;
        const int sw = (row & 7) << 4;
        #pragma unroll
        for (int ks = 0; ks < 2; ++ks) {
          bf16x8 bv = *(const bf16x8*)(lVc + row*128 + ((ks*64 + lhi*16) ^ sw));
          #pragma unroll
          for (int m = 0; m < 2; ++m)
            acc_o[m][c] = mfma_bf16(pa[m][ks], bv, acc_o[m][c]);
        }
      }
      __builtin_amdgcn_s_setprio(0);
    }
    __syncthreads();
  }

  if (sp == 2) {
    // direct: normalize and write
    #pragma unroll
    for (int m = 0; m < 2; ++m)
      #pragma unroll
      for (int r = 0; r < 4; ++r) {
        const int tq = q0w + m*16 + lhi*4 + r;
        const float invl = 1.0f / acc_l[m][r];
        const size_t obase = ((size_t)b*T_ + tq)*C_ + h*D_;
        #pragma unroll
        for (int c = 0; c < 4; ++c)
          aout[obase + c*16 + l15] = (__bf16)(acc_o[m][c][r] * invl);
      }
  } else {
    // partial: unnormalized O (f32) + per-row m, l
    const int pidx = ((qblock - 8)*2 + sp)*64 + bh;
    float* po = pO + (size_t)pidx*128*64;
    float* pm = pM + pidx*128;
    float* pl = pL + pidx*128;
    #pragma unroll
    for (int m = 0; m < 2; ++m)
      #pragma unroll
      for (int r = 0; r < 4; ++r) {
        const int rw = wave*32 + m*16 + lhi*4 + r;
        if (l15 == 0) { pm[rw] = m_w; pl[rw] = acc_l[m][r]; }
        #pragma unroll
        for (int c = 0; c < 4; ++c)
          po[(size_t)rw*64 + c*16 + l15] = acc_o[m][c][r];
      }
  }
}

// merge the two kv-split partials for qblock in [8,16)
__global__ void __launch_bounds__(256)
attn_combine(const float* __restrict__ pO, const float* __restrict__ pM,
             const float* __restrict__ pL, __bf16* __restrict__ aout)
{
  const int g = blockIdx.x;            // 512: qb8*64 + bh
  const int qb8 = g >> 6, bh = g & 63;
  const int p0 = (qb8*2)*64 + bh, p1 = (qb8*2 + 1)*64 + bh;
  const int row = threadIdx.x >> 1, ch = threadIdx.x & 1;
  const float m0 = pM[p0*128 + row], m1 = pM[p1*128 + row];
  const float l0 = pL[p0*128 + row], l1 = pL[p1*128 + row];
  const float M = fmaxf(m0, m1);
  const float w0 = __builtin_amdgcn_exp2f(m0 - M);
  const float w1 = __builtin_amdgcn_exp2f(m1 - M);
  const float inv = 1.0f / (l0*w0 + l1*w1);
  const int b = bh >> 4, h = bh & 15;
  const int t = (qb8 + 8)*128 + row;
  const float* o0 = pO + ((size_t)p0*128 + row)*64 + ch*32;
  const float* o1 = pO + ((size_t)p1*128 + row)*64 + ch*32;
  __bf16* dst = aout + ((size_t)b*T_ + t)*C_ + h*D_ + ch*32;
  #pragma unroll
  for (int j = 0; j < 32; j += 4) {
    float4 a = *(const float4*)(o0 + j);
    float4 c = *(const float4*)(o1 + j);
    bf16x4 rr;
    rr[0] = (__bf16)((a.x*w0 + c.x*w1) * inv);
    rr[1] = (__bf16)((a.y*w0 + c.y*w1) * inv);
    rr[2] = (__bf16)((a.z*w0 + c.z*w1) * inv);
    rr[3] = (__bf16)((a.w*w0 + c.w*w1) * inv);
    *(bf16x4*)(dst + j) = rr;
  }
}

// ---------------- launch ----------------

extern "C" void kernel_launch(void* const* d_in, const int* in_sizes, int n_in,
                              void* d_out, int out_size, void* d_ws, size_t ws_size,
                              hipStream_t stream)
{
  const float* x     = (const float*)d_in[0];
  const int*   amask = (const int*)d_in[1];
  const float* Wqkv  = (const float*)d_in[2];
  const float* Wout  = (const float*)d_in[3];
  const float* bout  = (const float*)d_in[4];
  float* out = (float*)d_out;

  char* w = (char*)d_ws;
  __bf16* xb    = (__bf16*)w;  w += (size_t)M_TOT*C_*2;       // 16 MB (reused as vtb after QKV GEMM)
  __bf16* wqkvT = (__bf16*)w;  w += (size_t)3072*1024*2;      // 6 MB
  __bf16* woutT = (__bf16*)w;  w += (size_t)1024*1024*2;      // 2 MB
  __bf16* qb    = (__bf16*)w;  w += (size_t)B_*H_*T_*D_*2;    // 16 MB
  __bf16* kb    = (__bf16*)w;  w += (size_t)B_*H_*T_*D_*2;    // 16 MB
  __bf16* vb    = (__bf16*)w;  w += (size_t)B_*H_*T_*D_*2;    // 16 MB
  __bf16* aob   = (__bf16*)w;  w += (size_t)M_TOT*C_*2;       // 16 MB
  float*  cosT  = (float*)w;   w += (size_t)T_*32*4;
  float*  sinT  = (float*)w;   w += (size_t)T_*32*4;
  float*  pO    = (float*)w;   w += (size_t)1024*128*64*4;    // 33.5 MB split partials
  float*  pM    = (float*)w;   w += (size_t)1024*128*4;
  float*  pL    = (float*)w;   w += (size_t)1024*128*4;
  __bf16* vtb   = xb;   // xb dead after QKV GEMM; alias for V^T

  f32_to_bf16_k<<<(M_TOT*C_/4 + 255)/256, 256, 0, stream>>>(x, xb, M_TOT*C_/4);
  transpose_to_bf16<<<dim3(96, 32), 256, 0, stream>>>(Wqkv, wqkvT, 1024, 3072);
  transpose_to_bf16<<<dim3(32, 32), 256, 0, stream>>>(Wout, woutT, 1024, 1024);
  rope_tables_k<<<(T_*32)/256, 256, 0, stream>>>(cosT, sinT);

  gemm256_qkv<<<dim3(384), 512, 0, stream>>>(xb, wqkvT, qb, kb, vb, cosT, sinT);

  vtrans_k<<<dim3(T_/64, B_*H_), 256, 0, stream>>>(vb, vtb);

  attn_kernel<<<dim3(1536), 256, 0, stream>>>(qb, kb, vtb, amask, aob, pO, pM, pL);
  attn_combine<<<dim3(512), 256, 0, stream>>>(pO, pM, pL, aob);

  gemm_out<<<dim3(64*8), 256, 0, stream>>>(
      aob, woutT, 1024, out, bout);
}

// Round 4
// 225.393 us; speedup vs baseline: 1.2546x; 1.0842x over previous
//
#include <hip/hip_runtime.h>
#include <hip/hip_bf16.h>
#include <math.h>

typedef __attribute__((ext_vector_type(8))) __bf16 bf16x8;
typedef __attribute__((ext_vector_type(4))) __bf16 bf16x4;
typedef __attribute__((ext_vector_type(4))) float f32x4;

#define B_ 4
#define T_ 2048
#define C_ 1024
#define H_ 16
#define D_ 64
#define M_TOT (B_*T_)

static __device__ __forceinline__ f32x4 mfma_bf16(bf16x8 a, bf16x8 b, f32x4 c) {
  return __builtin_amdgcn_mfma_f32_16x16x32_bf16(a, b, c, 0, 0, 0);
}

static __device__ __forceinline__ void gload_lds16(const void* g, void* l) {
  __builtin_amdgcn_global_load_lds((const __attribute__((address_space(1))) void*)g,
                                   (__attribute__((address_space(3))) void*)l, 16, 0, 0);
}

// ---------------- converts ----------------

__global__ void f32_to_bf16_k(const float* __restrict__ in, __bf16* __restrict__ out, int n4) {
  int i = blockIdx.x * blockDim.x + threadIdx.x;
  if (i < n4) {
    float4 v = ((const float4*)in)[i];
    bf16x4 o = { (__bf16)v.x, (__bf16)v.y, (__bf16)v.z, (__bf16)v.w };
    *(bf16x4*)(out + (size_t)i*4) = o;
  }
}

// out[n][k] = in[k][n], out bf16 (N x K), in fp32 (K x N)
__global__ void transpose_to_bf16(const float* __restrict__ in, __bf16* __restrict__ out, int K, int N) {
  __shared__ float tile[32][33];
  int n0 = blockIdx.x * 32, k0 = blockIdx.y * 32;
  int tx = threadIdx.x & 31, ty = threadIdx.x >> 5;
  #pragma unroll
  for (int r = ty; r < 32; r += 8) tile[r][tx] = in[(size_t)(k0 + r)*N + n0 + tx];
  __syncthreads();
  #pragma unroll
  for (int r = ty; r < 32; r += 8) out[(size_t)(n0 + r)*K + k0 + tx] = (__bf16)tile[tx][r];
}

__global__ void rope_tables_k(float* __restrict__ cosT, float* __restrict__ sinT) {
  int idx = blockIdx.x * 256 + threadIdx.x;   // T_*32 total
  int t = idx >> 5, d = idx & 31;
  float inv = powf(10000.0f, -((float)(2*d)) / 64.0f);
  float ang = (float)t * inv;
  cosT[idx] = cosf(ang);
  sinT[idx] = sinf(ang);
}

// V [bh][t][d] -> Vt [bh][d][t]
__global__ void __launch_bounds__(256)
vtrans_k(const __bf16* __restrict__ v, __bf16* __restrict__ vt) {
  __shared__ __bf16 tile[64][72];
  const int tid = threadIdx.x;
  const int bh = blockIdx.y;
  const int t0 = blockIdx.x * 64;
  const __bf16* src = v + ((size_t)bh*T_ + t0)*D_;
  #pragma unroll
  for (int c = 0; c < 2; ++c) {
    int idx = tid + c*256;
    int row = idx >> 3, col8 = (idx & 7) * 8;
    *(bf16x8*)&tile[row][col8] = *(const bf16x8*)(src + row*D_ + col8);
  }
  __syncthreads();
  __bf16* dst = vt + (size_t)bh*D_*T_ + t0;
  #pragma unroll
  for (int c = 0; c < 2; ++c) {
    int idx = tid + c*256;
    int d = idx >> 3, t8 = (idx & 7) * 8;
    bf16x8 ov;
    #pragma unroll
    for (int j = 0; j < 8; ++j) ov[j] = tile[t8 + j][d];
    *(bf16x8*)(dst + (size_t)d*T_ + t8) = ov;
  }
}

// ---------------- QKV GEMM: 256x256 tile, BK=64, 8 waves, dbuf, 1-barrier/K-tile ----
#define GBK 64

__global__ void __launch_bounds__(512, 2)
gemm256_qkv(const __bf16* __restrict__ A, const __bf16* __restrict__ Bt,
            __bf16* __restrict__ qout, __bf16* __restrict__ kout, __bf16* __restrict__ vout,
            const float* __restrict__ cosT, const float* __restrict__ sinT)
{
  __shared__ __attribute__((aligned(16))) __bf16 lA[2][256*GBK];  // 32 KB each
  __shared__ __attribute__((aligned(16))) __bf16 lB[2][256*GBK];
  const int tid = threadIdx.x;
  const int lane = tid & 63, wave = tid >> 6;
  const int wr = wave >> 2, wc = wave & 3;       // 2 x 4 wave grid
  const int l15 = lane & 15, lhi = lane >> 4;

  const int id = blockIdx.x;                     // 384 blocks (384 % 8 == 0)
  const int n8 = gridDim.x >> 3;
  const int swz = (id & 7) * n8 + (id >> 3);
  const int row0 = (swz & 31) * 256;             // M/256 = 32
  const int col0 = (swz >> 5) * 256;             // N/256 = 12

  f32x4 acc[8][4] = {};

  const size_t lda = 1024 * 2;                   // K bytes per row
  const char* Abase = (const char*)A + (size_t)row0 * lda;
  const char* Bbase = (const char*)Bt + (size_t)col0 * lda;

  auto STAGE = [&](int kt, int s) {
    #pragma unroll
    for (int c = 0; c < 4; ++c) {
      const int L = tid*16 + c*8192;
      const int row = L >> 7, colb = L & 127;
      const int sb = colb ^ ((row & 7) << 4);    // inverse swizzle on global source
      gload_lds16(Abase + (size_t)row*lda + kt*128 + sb, (char*)lA[s] + L);
      gload_lds16(Bbase + (size_t)row*lda + kt*128 + sb, (char*)lB[s] + L);
    }
  };

  STAGE(0, 0);
  asm volatile("s_waitcnt vmcnt(0)" ::: "memory");
  __syncthreads();

  for (int kt = 0; kt < 16; ++kt) {
    const int cur = kt & 1;
    if (kt < 15) STAGE(kt + 1, cur ^ 1);

    // B fragments: read once per K-tile (4 n-frags x 2 k-steps)
    bf16x8 bfr[4][2];
    #pragma unroll
    for (int n = 0; n < 4; ++n) {
      const int row = wc*64 + n*16 + l15;
      const int sw = (row & 7) << 4;
      #pragma unroll
      for (int ks = 0; ks < 2; ++ks)
        bfr[n][ks] = *(const bf16x8*)((const char*)lB[cur] + row*128 + ((ks*64 + lhi*16) ^ sw));
    }
    // 4 phases: 2 m-rows each, 16 MFMA per phase
    #pragma unroll
    for (int mp = 0; mp < 4; ++mp) {
      bf16x8 af[2][2];
      #pragma unroll
      for (int mm = 0; mm < 2; ++mm) {
        const int row = wr*128 + (mp*2 + mm)*16 + l15;
        const int sw = (row & 7) << 4;
        #pragma unroll
        for (int ks = 0; ks < 2; ++ks)
          af[mm][ks] = *(const bf16x8*)((const char*)lA[cur] + row*128 + ((ks*64 + lhi*16) ^ sw));
      }
      __builtin_amdgcn_s_setprio(1);
      #pragma unroll
      for (int mm = 0; mm < 2; ++mm)
        #pragma unroll
        for (int n = 0; n < 4; ++n)
          #pragma unroll
          for (int ks = 0; ks < 2; ++ks)
            acc[mp*2 + mm][n] = mfma_bf16(af[mm][ks], bfr[n][ks], acc[mp*2 + mm][n]);
      __builtin_amdgcn_s_setprio(0);
    }

    asm volatile("s_waitcnt vmcnt(0)" ::: "memory");
    __syncthreads();
  }

  // epilogue: RoPE on q,k; scatter to (B,H,T,D); q pre-scaled by 0.125*log2e
  const int slot = (col0 >> 6) + wc;
  const int which = slot >> 4;
  const int h = slot & 15;
  const float fsc = (which == 0) ? 0.18033688011112042f : 1.0f;
  #pragma unroll
  for (int m = 0; m < 8; ++m) {
    #pragma unroll
    for (int r = 0; r < 4; ++r) {
      const int grow = row0 + wr*128 + m*16 + lhi*4 + r;
      const int b = grow >> 11, t = grow & 2047;
      const size_t obase = ((size_t)(b*H_ + h)*T_ + t)*D_;
      if (which == 2) {
        #pragma unroll
        for (int n = 0; n < 4; ++n)
          vout[obase + n*16 + l15] = (__bf16)acc[m][n][r];
      } else {
        __bf16* dst = (which == 0) ? qout : kout;
        #pragma unroll
        for (int n = 0; n < 2; ++n) {
          const int d1 = n*16 + l15;            // [0,32)
          const float c = cosT[t*32 + d1];
          const float s = sinT[t*32 + d1];
          const float x1 = acc[m][n][r];
          const float x2 = acc[m][n+2][r];
          dst[obase + d1]      = (__bf16)((x1*c - x2*s) * fsc);
          dst[obase + d1 + 32] = (__bf16)((x1*s + x2*c) * fsc);
        }
      }
    }
  }
}

// ---------------- out-proj GEMM (m97 structure: 128x128 tile, BK=64, 4 waves) -------
#define BM 128
#define BN 128
#define BK 64

__global__ void __launch_bounds__(256)
gemm_out(const __bf16* __restrict__ A, const __bf16* __restrict__ Bt, int K,
         float* __restrict__ fout, const float* __restrict__ bias)
{
  __shared__ __bf16 lA[BM*BK];
  __shared__ __bf16 lB[BN*BK];
  const int tid = threadIdx.x;
  const int lane = tid & 63, wave = tid >> 6;
  const int wr = wave >> 1, wc = wave & 1;
  const int l15 = lane & 15, lhi = lane >> 4;

  const int id = blockIdx.x;
  const int n8 = gridDim.x >> 3;
  const int swz = (id & 7) * n8 + (id >> 3);
  const int row0 = (swz & 63) * BM;
  const int col0 = (swz >> 6) * BN;

  f32x4 acc[4][4] = {};

  const int stago = wave*1024 + lane*16;
  const size_t arow0 = (size_t)row0 * (size_t)(K*2);
  const size_t brow0 = (size_t)col0 * (size_t)(K*2);

  for (int k0 = 0; k0 < K; k0 += BK) {
    #pragma unroll
    for (int r = 0; r < 4; ++r) {
      int ob = stago + r*4096;
      int row = ob >> 7;
      int colb = ob & 127;
      gload_lds16((const char*)A + arow0 + (size_t)row*(size_t)(K*2) + (size_t)(k0*2 + colb),
                  (char*)lA + ob);
      gload_lds16((const char*)Bt + brow0 + (size_t)row*(size_t)(K*2) + (size_t)(k0*2 + colb),
                  (char*)lB + ob);
    }
    __syncthreads();
    #pragma unroll
    for (int kk = 0; kk < BK; kk += 32) {
      bf16x8 af[4], bfr[4];
      #pragma unroll
      for (int m = 0; m < 4; ++m)
        af[m] = *(const bf16x8*)&lA[(wr*64 + m*16 + l15)*BK + kk + lhi*8];
      #pragma unroll
      for (int n = 0; n < 4; ++n)
        bfr[n] = *(const bf16x8*)&lB[(wc*64 + n*16 + l15)*BK + kk + lhi*8];
      #pragma unroll
      for (int m = 0; m < 4; ++m)
        #pragma unroll
        for (int n = 0; n < 4; ++n)
          acc[m][n] = mfma_bf16(af[m], bfr[n], acc[m][n]);
    }
    __syncthreads();
  }

  #pragma unroll
  for (int m = 0; m < 4; ++m) {
    #pragma unroll
    for (int r = 0; r < 4; ++r) {
      const int grow = row0 + wr*64 + m*16 + lhi*4 + r;
      #pragma unroll
      for (int n = 0; n < 4; ++n) {
        const int gcol = col0 + wc*64 + n*16 + l15;
        fout[(size_t)grow*1024 + gcol] = acc[m][n][r] + bias[gcol];
      }
    }
  }
}

// ---------------- flash attention: split-KV + LPT, Q-in-LDS, 3 blocks/CU ----------
// Residency theory: default build used ~116 VGPR + ~60 AGPR (unified file) ->
// 2048/~180 -> 8 waves/CU -> 2 blocks/CU -> 20% occupancy (measured, grid-
// independent). Fix: move Q fragments to LDS (frees 32 loop-carried regs) and
// declare __launch_bounds__(256,3) (total reg budget ~170 -> fits w/o spill).
// LDS 48KB -> 3 blocks/CU. Spill canary: WRITE_SIZE must stay ~50MB.
#define THR_LOG2 8.0f

// group (blockIdx>>6) -> qblock, split (0/1 = kv half, 2 = direct full range)
static __device__ const char QB_TAB[24] = {15,15,7,14,14,13,13,6,12,12,11,11,5,10,10,9,9,4,8,8,3,2,1,0};
static __device__ const char SP_TAB[24] = { 0, 1,2, 0, 1, 0, 1,2, 0, 1, 0, 1,2, 0, 1,0,1,2,0,1,2,2,2,2};

__global__ void __launch_bounds__(256, 3)
attn_kernel(const __bf16* __restrict__ q, const __bf16* __restrict__ k,
            const __bf16* __restrict__ vt, const int* __restrict__ amask,
            __bf16* __restrict__ aout,
            float* __restrict__ pO, float* __restrict__ pM, float* __restrict__ pL)
{
  __shared__ __attribute__((aligned(16))) __bf16 lK[64*64];    // 8 KB
  __shared__ __attribute__((aligned(16))) __bf16 lVt[64*64];   // 8 KB
  __shared__ __attribute__((aligned(16))) __bf16 lP[4][32*64]; // 16 KB
  __shared__ __attribute__((aligned(16))) __bf16 lQ[128*64];   // 16 KB
  const int tid = threadIdx.x;
  const int lane = tid & 63, wave = tid >> 6;
  const int l15 = lane & 15, lhi = lane >> 4;

  const int g = blockIdx.x >> 6;
  const int bh = blockIdx.x & 63;
  const int qblock = QB_TAB[g];
  const int sp = SP_TAB[g];
  const int kb0   = (sp == 1) ? (qblock + 1) : 0;
  const int kbend = (sp == 0) ? (qblock + 1) : (2*qblock + 2);

  const int b = bh >> 4, h = bh & 15;
  const size_t kvbase = (size_t)bh * T_ * D_;
  const char* kbase  = (const char*)(k + kvbase);
  const char* vtbase = (const char*)(vt + kvbase);
  char* lPw = (char*)lP[wave];

  const int q0w = qblock*128 + wave*32;

  // stage Q tile (128 rows x 128B) once; swizzled like lK
  {
    const char* qgbase = (const char*)(q + kvbase) + (size_t)qblock*128*128;
    #pragma unroll
    for (int c = 0; c < 4; ++c) {
      const int L = tid*16 + c*4096;
      const int row = L >> 7;
      const int sb = (L & 127) ^ ((row & 7) << 4);
      gload_lds16(qgbase + (size_t)row*128 + sb, (char*)lQ + L);
    }
  }

  f32x4 acc_o[2][4] = {};
  f32x4 acc_l[2] = {};
  float m_w = -3e37f;

  for (int kb = kb0; kb < kbend; ++kb) {
    #pragma unroll
    for (int c = 0; c < 2; ++c) {
      const int L = tid*16 + c*4096;
      const int row = L >> 7;
      const int sb  = (L & 127) ^ ((row & 7) << 4);
      gload_lds16(kbase  + (size_t)(kb*64 + row)*128 + sb, (char*)lK + L);
      gload_lds16(vtbase + (size_t)row*(T_*2) + (size_t)kb*128 + sb, (char*)lVt + L);
    }
    __syncthreads();

    if (kb*64 <= q0w + 31) {
      const char* lKc = (const char*)lK;
      const char* lVc = (const char*)lVt;
      const char* lQw = (const char*)lQ + (wave*32)*128;
      asm volatile("" : "+v"(lQw));   // defeat cross-iteration hoist of Q reads

      // Q fragments from LDS (re-read each iteration -> not loop-carried regs)
      bf16x8 aq[2][2];
      #pragma unroll
      for (int m = 0; m < 2; ++m) {
        const int lr = m*16 + l15;
        const int sw = (lr & 7) << 4;
        #pragma unroll
        for (int ks = 0; ks < 2; ++ks)
          aq[m][ks] = *(const bf16x8*)(lQw + lr*128 + ((ks*64 + lhi*16) ^ sw));
      }

      f32x4 sc[2][4] = {};
      __builtin_amdgcn_s_setprio(1);
      #pragma unroll
      for (int n = 0; n < 4; ++n) {
        const int row = n*16 + l15;
        const int sw = (row & 7) << 4;
        #pragma unroll
        for (int ks = 0; ks < 2; ++ks) {
          bf16x8 bk = *(const bf16x8*)(lKc + row*128 + ((ks*64 + lhi*16) ^ sw));
          #pragma unroll
          for (int m = 0; m < 2; ++m)
            sc[m][n] = mfma_bf16(aq[m][ks], bk, sc[m][n]);
        }
      }
      __builtin_amdgcn_s_setprio(0);

      if (kb*64 + 63 > q0w) {
        #pragma unroll
        for (int m = 0; m < 2; ++m)
          #pragma unroll
          for (int r = 0; r < 4; ++r) {
            const int tq = q0w + m*16 + lhi*4 + r;
            #pragma unroll
            for (int n = 0; n < 4; ++n)
              if (kb*64 + n*16 + l15 > tq) sc[m][n][r] = -3e37f;
          }
      }

      f32x4 vm = sc[0][0];
      #pragma unroll
      for (int m = 0; m < 2; ++m)
        #pragma unroll
        for (int n = 0; n < 4; ++n) {
          if (m == 0 && n == 0) continue;
          #pragma unroll
          for (int r = 0; r < 4; ++r) vm[r] = fmaxf(vm[r], sc[m][n][r]);
        }
      float tmax = fmaxf(fmaxf(vm[0], vm[1]), fmaxf(vm[2], vm[3]));
      #pragma unroll
      for (int off = 1; off < 64; off <<= 1)
        tmax = fmaxf(tmax, __shfl_xor(tmax, off));

      if (tmax > m_w + THR_LOG2) {
        const float corr = __builtin_amdgcn_exp2f(m_w - tmax);
        #pragma unroll
        for (int m = 0; m < 2; ++m) {
          #pragma unroll
          for (int c = 0; c < 4; ++c) acc_o[m][c] *= corr;
          acc_l[m] *= corr;
        }
        m_w = tmax;
      }

      float mk[4];
      #pragma unroll
      for (int n = 0; n < 4; ++n)
        mk[n] = (amask[b*T_ + kb*64 + n*16 + l15] != 0) ? m_w : 3e37f;

      #pragma unroll
      for (int m = 0; m < 2; ++m)
        #pragma unroll
        for (int r = 0; r < 4; ++r) {
          const int row = m*16 + lhi*4 + r;
          const int sw = (row & 7) << 4;
          #pragma unroll
          for (int n = 0; n < 4; ++n) {
            const float p = __builtin_amdgcn_exp2f(sc[m][n][r] - mk[n]);
            *(__bf16*)(lPw + row*128 + ((((n*16 + l15)*2)) ^ sw)) = (__bf16)p;
          }
        }

      bf16x8 pa[2][2];
      #pragma unroll
      for (int m = 0; m < 2; ++m) {
        const int row = m*16 + l15;
        const int sw = (row & 7) << 4;
        #pragma unroll
        for (int ks = 0; ks < 2; ++ks)
          pa[m][ks] = *(const bf16x8*)(lPw + row*128 + ((ks*64 + lhi*16) ^ sw));
      }

      __builtin_amdgcn_s_setprio(1);
      const __bf16 one = (__bf16)1.0f;
      const bf16x8 vone = {one, one, one, one, one, one, one, one};
      #pragma unroll
      for (int m = 0; m < 2; ++m)
        #pragma unroll
        for (int ks = 0; ks < 2; ++ks)
          acc_l[m] = mfma_bf16(pa[m][ks], vone, acc_l[m]);

      #pragma unroll
      for (int c = 0; c < 4; ++c) {
        const int row = c*16 + l15;
        const int sw = (row & 7) << 4;
        #pragma unroll
        for (int ks = 0; ks < 2; ++ks) {
          bf16x8 bv = *(const bf16x8*)(lVc + row*128 + ((ks*64 + lhi*16) ^ sw));
          #pragma unroll
          for (int m = 0; m < 2; ++m)
            acc_o[m][c] = mfma_bf16(pa[m][ks], bv, acc_o[m][c]);
        }
      }
      __builtin_amdgcn_s_setprio(0);
    }
    __syncthreads();
  }

  if (sp == 2) {
    // direct: normalize and write
    #pragma unroll
    for (int m = 0; m < 2; ++m)
      #pragma unroll
      for (int r = 0; r < 4; ++r) {
        const int tq = q0w + m*16 + lhi*4 + r;
        const float invl = 1.0f / acc_l[m][r];
        const size_t obase = ((size_t)b*T_ + tq)*C_ + h*D_;
        #pragma unroll
        for (int c = 0; c < 4; ++c)
          aout[obase + c*16 + l15] = (__bf16)(acc_o[m][c][r] * invl);
      }
  } else {
    // partial: unnormalized O (f32) + per-row m, l
    const int pidx = ((qblock - 8)*2 + sp)*64 + bh;
    float* po = pO + (size_t)pidx*128*64;
    float* pm = pM + pidx*128;
    float* pl = pL + pidx*128;
    #pragma unroll
    for (int m = 0; m < 2; ++m)
      #pragma unroll
      for (int r = 0; r < 4; ++r) {
        const int rw = wave*32 + m*16 + lhi*4 + r;
        if (l15 == 0) { pm[rw] = m_w; pl[rw] = acc_l[m][r]; }
        #pragma unroll
        for (int c = 0; c < 4; ++c)
          po[(size_t)rw*64 + c*16 + l15] = acc_o[m][c][r];
      }
  }
}

// merge the two kv-split partials for qblock in [8,16)
__global__ void __launch_bounds__(256)
attn_combine(const float* __restrict__ pO, const float* __restrict__ pM,
             const float* __restrict__ pL, __bf16* __restrict__ aout)
{
  const int g = blockIdx.x;            // 512: qb8*64 + bh
  const int qb8 = g >> 6, bh = g & 63;
  const int p0 = (qb8*2)*64 + bh, p1 = (qb8*2 + 1)*64 + bh;
  const int row = threadIdx.x >> 1, ch = threadIdx.x & 1;
  const float m0 = pM[p0*128 + row], m1 = pM[p1*128 + row];
  const float l0 = pL[p0*128 + row], l1 = pL[p1*128 + row];
  const float M = fmaxf(m0, m1);
  const float w0 = __builtin_amdgcn_exp2f(m0 - M);
  const float w1 = __builtin_amdgcn_exp2f(m1 - M);
  const float inv = 1.0f / (l0*w0 + l1*w1);
  const int b = bh >> 4, h = bh & 15;
  const int t = (qb8 + 8)*128 + row;
  const float* o0 = pO + ((size_t)p0*128 + row)*64 + ch*32;
  const float* o1 = pO + ((size_t)p1*128 + row)*64 + ch*32;
  __bf16* dst = aout + ((size_t)b*T_ + t)*C_ + h*D_ + ch*32;
  #pragma unroll
  for (int j = 0; j < 32; j += 4) {
    float4 a = *(const float4*)(o0 + j);
    float4 c = *(const float4*)(o1 + j);
    bf16x4 rr;
    rr[0] = (__bf16)((a.x*w0 + c.x*w1) * inv);
    rr[1] = (__bf16)((a.y*w0 + c.y*w1) * inv);
    rr[2] = (__bf16)((a.z*w0 + c.z*w1) * inv);
    rr[3] = (__bf16)((a.w*w0 + c.w*w1) * inv);
    *(bf16x4*)(dst + j) = rr;
  }
}

// ---------------- launch ----------------

extern "C" void kernel_launch(void* const* d_in, const int* in_sizes, int n_in,
                              void* d_out, int out_size, void* d_ws, size_t ws_size,
                              hipStream_t stream)
{
  const float* x     = (const float*)d_in[0];
  const int*   amask = (const int*)d_in[1];
  const float* Wqkv  = (const float*)d_in[2];
  const float* Wout  = (const float*)d_in[3];
  const float* bout  = (const float*)d_in[4];
  float* out = (float*)d_out;

  char* w = (char*)d_ws;
  __bf16* xb    = (__bf16*)w;  w += (size_t)M_TOT*C_*2;       // 16 MB (reused as vtb after QKV GEMM)
  __bf16* wqkvT = (__bf16*)w;  w += (size_t)3072*1024*2;      // 6 MB
  __bf16* woutT = (__bf16*)w;  w += (size_t)1024*1024*2;      // 2 MB
  __bf16* qb    = (__bf16*)w;  w += (size_t)B_*H_*T_*D_*2;    // 16 MB
  __bf16* kb    = (__bf16*)w;  w += (size_t)B_*H_*T_*D_*2;    // 16 MB
  __bf16* vb    = (__bf16*)w;  w += (size_t)B_*H_*T_*D_*2;    // 16 MB
  __bf16* aob   = (__bf16*)w;  w += (size_t)M_TOT*C_*2;       // 16 MB
  float*  cosT  = (float*)w;   w += (size_t)T_*32*4;
  float*  sinT  = (float*)w;   w += (size_t)T_*32*4;
  float*  pO    = (float*)w;   w += (size_t)1024*128*64*4;    // 33.5 MB split partials
  float*  pM    = (float*)w;   w += (size_t)1024*128*4;
  float*  pL    = (float*)w;   w += (size_t)1024*128*4;
  __bf16* vtb   = xb;   // xb dead after QKV GEMM; alias for V^T

  f32_to_bf16_k<<<(M_TOT*C_/4 + 255)/256, 256, 0, stream>>>(x, xb, M_TOT*C_/4);
  transpose_to_bf16<<<dim3(96, 32), 256, 0, stream>>>(Wqkv, wqkvT, 1024, 3072);
  transpose_to_bf16<<<dim3(32, 32), 256, 0, stream>>>(Wout, woutT, 1024, 1024);
  rope_tables_k<<<(T_*32)/256, 256, 0, stream>>>(cosT, sinT);

  gemm256_qkv<<<dim3(384), 512, 0, stream>>>(xb, wqkvT, qb, kb, vb, cosT, sinT);

  vtrans_k<<<dim3(T_/64, B_*H_), 256, 0, stream>>>(vb, vtb);

  attn_kernel<<<dim3(1536), 256, 0, stream>>>(qb, kb, vtb, amask, aob, pO, pM, pL);
  attn_combine<<<dim3(512), 256, 0, stream>>>(pO, pM, pL, aob);

  gemm_out<<<dim3(64*8), 256, 0, stream>>>(
      aob, woutT, 1024, out, bout);
}